// Round 10
// baseline (935.181 us; speedup 1.0000x reference)
//
#include <hip/hip_runtime.h>
#include <hip/hip_fp8.h>
#include <hip/hip_fp16.h>
#include <stdint.h>

#define FP8_MAX_V 448.0f

typedef float f32x16 __attribute__((ext_vector_type(16)));
typedef int i32x4 __attribute__((ext_vector_type(4)));
typedef int i32x8 __attribute__((ext_vector_type(8)));

__device__ __forceinline__ uint8_t cvt_fp8(float v) {
    return __hip_cvt_float_to_fp8(fminf(fmaxf(v, -FP8_MAX_V), FP8_MAX_V),
                                  __HIP_SATFINITE, __HIP_E4M3);
}

// ---------------- amax (per-tensor, exact) ----------------
__global__ void fp8lin_init(unsigned* amax_bits) {
    *amax_bits = 0u;
}

__global__ void fp8lin_amax(const float4* __restrict__ x, unsigned* __restrict__ amax_bits, long n4) {
    float m = 0.f;
    long stride = (long)gridDim.x * blockDim.x;
    for (long i = blockIdx.x * (long)blockDim.x + threadIdx.x; i < n4; i += stride) {
        float4 v = x[i];
        m = fmaxf(m, fmaxf(fmaxf(fabsf(v.x), fabsf(v.y)), fmaxf(fabsf(v.z), fabsf(v.w))));
    }
#pragma unroll
    for (int o = 32; o; o >>= 1) m = fmaxf(m, __shfl_xor(m, o));
    if ((threadIdx.x & 63) == 0) atomicMax(amax_bits, __float_as_uint(m));
}

// ---------------- derive scales ONCE ----------------
__global__ void fp8lin_scales(const unsigned* __restrict__ amax_bits,
                              const float* __restrict__ wscale,
                              float* __restrict__ scales) {
    float xs = fmaxf(__uint_as_float(*amax_bits), 1e-12f) / FP8_MAX_V;
    scales[0] = xs;
    scales[1] = xs * wscale[0];
}

// ---------------- probe weight transport dtype ----------------
__global__ void fp8lin_probe(const uint32_t* __restrict__ w, unsigned* __restrict__ flag) {
    __shared__ unsigned s32, s16, s4;
    if (threadIdx.x == 0) { s32 = 0u; s16 = 0u; s4 = 0u; }
    __syncthreads();
    unsigned o32 = 0u, o16 = 0u, o4 = 0u;
    for (int i = threadIdx.x; i < 4096; i += 256) {
        uint32_t v = w[i];
        o32 |= v & 0x000FFFFFu;
        uint32_t h0 = v & 0xFFFFu, h1 = v >> 16;
        o16 |= (h0 & 0x7Fu) | (h1 & 0x7Fu);
        o4  |= (h0 & 0x0Fu) | (h1 & 0x0Fu);
    }
    atomicOr(&s32, o32); atomicOr(&s16, o16); atomicOr(&s4, o4);
    __syncthreads();
    if (threadIdx.x == 0)
        *flag = (s32 == 0u) ? 0u : (s16 == 0u) ? 1u : (s4 == 0u) ? 2u : 3u;
}

// ---------------- convert transported weight -> raw fp8 (exact) ----------------
__global__ void fp8lin_convw(const void* __restrict__ wsrc, const unsigned* __restrict__ flag,
                             uchar4* __restrict__ wq, long n4) {
    unsigned f = *flag;
    if (f == 3u) return;
    long stride = (long)gridDim.x * blockDim.x;
    if (f == 0u) {
        const float4* src = (const float4*)wsrc;
        for (long i = blockIdx.x * (long)blockDim.x + threadIdx.x; i < n4; i += stride) {
            float4 v = src[i];
            uchar4 o;
            o.x = cvt_fp8(v.x); o.y = cvt_fp8(v.y); o.z = cvt_fp8(v.z); o.w = cvt_fp8(v.w);
            wq[i] = o;
        }
    } else if (f == 1u) {
        const __half2* src = (const __half2*)wsrc;
        for (long i = blockIdx.x * (long)blockDim.x + threadIdx.x; i < n4; i += stride) {
            __half2 v0 = src[2 * i], v1 = src[2 * i + 1];
            uchar4 o;
            o.x = cvt_fp8(__half2float(v0.x)); o.y = cvt_fp8(__half2float(v0.y));
            o.z = cvt_fp8(__half2float(v1.x)); o.w = cvt_fp8(__half2float(v1.y));
            wq[i] = o;
        }
    } else {
        const ushort2* src = (const ushort2*)wsrc;
        for (long i = blockIdx.x * (long)blockDim.x + threadIdx.x; i < n4; i += stride) {
            ushort2 v0 = src[2 * i], v1 = src[2 * i + 1];
            uchar4 o;
            o.x = cvt_fp8(__uint_as_float((uint32_t)v0.x << 16));
            o.y = cvt_fp8(__uint_as_float((uint32_t)v0.y << 16));
            o.z = cvt_fp8(__uint_as_float((uint32_t)v1.x << 16));
            o.w = cvt_fp8(__uint_as_float((uint32_t)v1.y << 16));
            wq[i] = o;
        }
    }
}

// ---------------- quantize x -> fp8 e4m3fn ----------------
__global__ void fp8lin_quant(const float4* __restrict__ x, const float* __restrict__ scales,
                             uchar4* __restrict__ xq, long n4) {
    float s = scales[0];
    long stride = (long)gridDim.x * blockDim.x;
    for (long i = blockIdx.x * (long)blockDim.x + threadIdx.x; i < n4; i += stride) {
        float4 v = x[i];
        uchar4 o;
        o.x = cvt_fp8(v.x / s); o.y = cvt_fp8(v.y / s);
        o.z = cvt_fp8(v.z / s); o.w = cvt_fp8(v.w / s);
        xq[i] = o;
    }
}

// ---- fp8 GEMM: 256x128 tile, 4 waves, MX 32x32x64, A via LDS dbuf, B global->reg ----
#define BM 256
#define BN 128
#define BK 64
#define A_TILE 16384                  // 256 rows x 64 B
#define BUF_BYTES A_TILE              // A only in LDS
#define SMEM_BYTES (2 * BUF_BYTES)    // 32 KiB double-buffered

__device__ __forceinline__ void gload16(const uint8_t* src, uint8_t* ldst) {
    __builtin_amdgcn_global_load_lds(
        (const __attribute__((address_space(1))) uint32_t*)(uintptr_t)src,
        (__attribute__((address_space(3))) uint32_t*)(uintptr_t)ldst, 16, 0, 0);
}

#define WAITVM(N) asm volatile("s_waitcnt vmcnt(" #N ")" ::: "memory")
#define BARRIER() do { asm volatile("" ::: "memory"); __builtin_amdgcn_s_barrier(); \
                       asm volatile("" ::: "memory"); } while (0)

// load one 32B k-fragment from LDS (two ds_read_b128 at XOR-16 swizzled granules)
#define LDFRAG(dst, base, off) do {                                    \
    i32x4 _lo = *(const i32x4*)((base) + (off));                       \
    i32x4 _hi = *(const i32x4*)((base) + ((off) ^ 16));                \
    dst[0] = _lo[0]; dst[1] = _lo[1]; dst[2] = _lo[2]; dst[3] = _lo[3];\
    dst[4] = _hi[0]; dst[5] = _hi[1]; dst[6] = _hi[2]; dst[7] = _hi[3];\
} while (0)

// load one 32B B-fragment straight from global (2x dwordx4, full lines consumed)
#define LOADB(bv, src, koff) do {                                      \
    const uint8_t* _p = (src) + (koff);                                \
    i32x4 _l0 = *(const i32x4*)(_p);                                   \
    i32x4 _l1 = *(const i32x4*)(_p + 16);                              \
    bv[0] = _l0[0]; bv[1] = _l0[1]; bv[2] = _l0[2]; bv[3] = _l0[3];    \
    bv[4] = _l1[0]; bv[5] = _l1[1]; bv[6] = _l1[2]; bv[7] = _l1[3];    \
} while (0)

// unit scales: e8m0 byte 0x7f = 2^0, every byte identical so opsel-immune
#define MFMA_MX(A, B, C) __builtin_amdgcn_mfma_scale_f32_32x32x64_f8f6f4( \
    (A), (B), (C), 0, 0, 0, (int)0x7f7f7f7f, 0, (int)0x7f7f7f7f)

// min-waves/EU = 2 (256-reg budget). Forcing 4 spilled the 128-reg acc (R6).
// 4-wave blocks, 2 independent blocks/CU (R8 mechanism); B bypasses LDS.
__global__ __launch_bounds__(256, 2) void fp8lin_gemm(
    const uint8_t* __restrict__ Aq,    // [M,K] fp8
    const uint8_t* __restrict__ Wraw,  // original weight ptr (valid iff flag==3)
    const uint8_t* __restrict__ Wconv, // converted fp8 (valid iff flag!=3)
    const unsigned* __restrict__ flag,
    const float* __restrict__ scales,
    const float* __restrict__ bias,
    float* __restrict__ out,
    int M, int N, int K) {
    extern __shared__ __align__(16) uint8_t smem[];

    const uint8_t* __restrict__ Wq = (*flag == 3u) ? Wraw : Wconv;

    const int tid = threadIdx.x;
    const int wid = tid >> 6;
    const int lane = tid & 63;
    const int wm = wid >> 1;   // 0..1  (M-wave, 128 rows each)
    const int wn = wid & 1;    // 0..1  (N-wave, 64 cols each)

    // ---- bijective XCD swizzle ----
    const int nbx = gridDim.x;                       // 128
    const int orig = blockIdx.y * nbx + blockIdx.x;
    const int cpx = (gridDim.x * gridDim.y) >> 3;    // 512
    const int swzb = (orig & 7) * cpx + (orig >> 3);
    const int brow = (swzb / nbx) * BM;
    const int bcol = (swzb % nbx) * BN;

    // ---- A staging: LDS linear [row][4 granules of 16B]; granule p holds global
    // granule p ^ ((row>>1)&3)  (pre-swizzled source column) ----
    const uint8_t* srcA[4];
#pragma unroll
    for (int j = 0; j < 4; ++j) {
        int c = tid + 256 * j;
        int r = c >> 2;
        int sc = ((c & 3) ^ ((r >> 1) & 3)) * 16;
        srcA[j] = Aq + (size_t)(brow + r) * K + sc;
    }
    const int ldsW = wid * 1024;   // wave-uniform LDS base (lane*16 implicit)

    // ---- LDS read addressing for A fragments ----
    const int l31 = lane & 31;
    const int q = lane >> 5;
    const int swzr = (l31 >> 1) & 3;          // row-base is mult of 32
    const int posl = (2 * q) ^ swzr;
    const int offA = (wm * 128 + l31) * 64 + posl * 16;  // + mi*2048

    // ---- B direct-from-global addressing: lane holds W row (bcol+wn*64+ni*32+l31),
    // bytes [32q, 32q+32) of each K-tile ----
    const uint8_t* srcB0 = Wq + (size_t)(bcol + wn * 64 + l31) * K + 32 * q;
    const uint8_t* srcB1 = srcB0 + (size_t)32 * K;   // ni=1: +32 rows

    f32x16 acc[4][2];
#pragma unroll
    for (int mi = 0; mi < 4; ++mi)
#pragma unroll
        for (int ni = 0; ni < 2; ++ni)
#pragma unroll
            for (int r = 0; r < 16; ++r) acc[mi][ni][r] = 0.0f;

    auto STAGEA = [&](int t, int ib) {
        size_t k0 = (size_t)t * BK;
        uint8_t* base = smem + ib * BUF_BYTES;
        gload16(srcA[0] + k0, base + ldsW);
        gload16(srcA[1] + k0, base + ldsW + 4096);
        gload16(srcA[2] + k0, base + ldsW + 8192);
        gload16(srcA[3] + k0, base + ldsW + 12288);
    };

    auto COMPUTE = [&](int ib, const i32x8& b0, const i32x8& b1) {
        const uint8_t* bA = smem + ib * BUF_BYTES;
        i32x8 a0, a1, a2, a3;
        LDFRAG(a0, bA, offA);
        LDFRAG(a1, bA, offA + 2048);
        __builtin_amdgcn_s_setprio(1);
        acc[0][0] = MFMA_MX(a0, b0, acc[0][0]);
        acc[1][0] = MFMA_MX(a1, b0, acc[1][0]);
        acc[0][1] = MFMA_MX(a0, b1, acc[0][1]);
        acc[1][1] = MFMA_MX(a1, b1, acc[1][1]);
        __builtin_amdgcn_s_setprio(0);
        LDFRAG(a2, bA, offA + 4096);
        LDFRAG(a3, bA, offA + 6144);
        __builtin_amdgcn_s_setprio(1);
        acc[2][0] = MFMA_MX(a2, b0, acc[2][0]);
        acc[3][0] = MFMA_MX(a3, b0, acc[3][0]);
        acc[2][1] = MFMA_MX(a2, b1, acc[2][1]);
        acc[3][1] = MFMA_MX(a3, b1, acc[3][1]);
        __builtin_amdgcn_s_setprio(0);
    };

    // Each tile's batch = exactly 8 VMEM ops (2x2 B dwordx4 + 4 gload16), so
    // WAITVM(8) drains precisely the previous tile's batch.
    const int NT = K / BK;  // 64 (even)
    i32x8 bE0, bE1, bO0, bO1;          // static names: even/odd tile B frags (rule #20)
    LOADB(bE0, srcB0, 0); LOADB(bE1, srcB1, 0);
    STAGEA(0, 0);
    for (int tp = 0; tp < NT; tp += 2) {
        // even tile tp: compute buf0/bE, prefetch tile tp+1 -> buf1/bO
        LOADB(bO0, srcB0, (size_t)(tp + 1) * BK);
        LOADB(bO1, srcB1, (size_t)(tp + 1) * BK);
        STAGEA(tp + 1, 1);
        WAITVM(8);
        BARRIER();
        COMPUTE(0, bE0, bE1);
        BARRIER();
        // odd tile tp+1: compute buf1/bO, prefetch tile tp+2 -> buf0/bE
        if (tp + 2 < NT) {
            LOADB(bE0, srcB0, (size_t)(tp + 2) * BK);
            LOADB(bE1, srcB1, (size_t)(tp + 2) * BK);
            STAGEA(tp + 2, 0);
            WAITVM(8);
        } else {
            WAITVM(0);
        }
        BARRIER();
        COMPUTE(1, bO0, bO1);
        BARRIER();
    }

    // ---- epilogue: 32x32 C/D layout col=lane&31, row=(reg&3)+8*(reg>>2)+4*q ----
    float s = scales[1];
    const int colg = bcol + wn * 64 + l31;
    const int rowg0 = brow + wm * 128 + 4 * q;
#pragma unroll
    for (int ni = 0; ni < 2; ++ni) {
        int col = colg + ni * 32;
        float bv = bias[col];
#pragma unroll
        for (int mi = 0; mi < 4; ++mi) {
            int rb = rowg0 + mi * 32;
#pragma unroll
            for (int reg = 0; reg < 16; ++reg) {
                int row = rb + (reg & 3) + 8 * (reg >> 2);
                __builtin_nontemporal_store(acc[mi][ni][reg] * s + bv,
                                            out + (size_t)row * N + col);
            }
        }
    }
}

extern "C" void kernel_launch(void* const* d_in, const int* in_sizes, int n_in,
                              void* d_out, int out_size, void* d_ws, size_t ws_size,
                              hipStream_t stream) {
    const float* x = (const float*)d_in[0];
    const void* w = d_in[1];
    const float* wscale = (const float*)d_in[2];
    const float* bias = (const float*)d_in[3];
    float* out = (float*)d_out;

    const int Bb = 4, S = 2048, K = 4096, N = 16384;
    const int M = Bb * S;
    const long nx = (long)M * K;
    const long nw = (long)N * K;

    unsigned* amax_bits = (unsigned*)d_ws;
    float* scales = (float*)((char*)d_ws + 16);
    unsigned* wflag = (unsigned*)((char*)d_ws + 32);
    uchar4* xq = (uchar4*)((char*)d_ws + 256);
    uchar4* wq = (uchar4*)((char*)d_ws + 256 + nx);

    fp8lin_init<<<1, 1, 0, stream>>>(amax_bits);
    fp8lin_probe<<<1, 256, 0, stream>>>((const uint32_t*)w, wflag);
    fp8lin_amax<<<2048, 256, 0, stream>>>((const float4*)x, amax_bits, nx / 4);
    fp8lin_scales<<<1, 1, 0, stream>>>(amax_bits, wscale, scales);
    fp8lin_quant<<<2048, 256, 0, stream>>>((const float4*)x, scales, xq, nx / 4);
    fp8lin_convw<<<2048, 256, 0, stream>>>(w, wflag, wq, nw / 4);

    dim3 grid(N / BN, M / BM);   // (128, 32) = 4096 blocks
    fp8lin_gemm<<<grid, 256, SMEM_BYTES, stream>>>((const uint8_t*)xq, (const uint8_t*)w,
                                                   (const uint8_t*)wq, wflag, scales, bias, out,
                                                   M, N, K);
}

// Round 11
// 788.285 us; speedup vs baseline: 1.1863x; 1.1863x over previous
//
#include <hip/hip_runtime.h>
#include <hip/hip_fp8.h>
#include <hip/hip_fp16.h>
#include <stdint.h>

#define FP8_MAX_V 448.0f

typedef float f32x16 __attribute__((ext_vector_type(16)));
typedef int i32x4 __attribute__((ext_vector_type(4)));
typedef int i32x8 __attribute__((ext_vector_type(8)));

__device__ __forceinline__ uint8_t cvt_fp8(float v) {
    return __hip_cvt_float_to_fp8(fminf(fmaxf(v, -FP8_MAX_V), FP8_MAX_V),
                                  __HIP_SATFINITE, __HIP_E4M3);
}

// ---------------- amax (per-tensor, exact) ----------------
__global__ void fp8lin_init(unsigned* amax_bits) {
    *amax_bits = 0u;
}

__global__ void fp8lin_amax(const float4* __restrict__ x, unsigned* __restrict__ amax_bits, long n4) {
    float m = 0.f;
    long stride = (long)gridDim.x * blockDim.x;
    for (long i = blockIdx.x * (long)blockDim.x + threadIdx.x; i < n4; i += stride) {
        float4 v = x[i];
        m = fmaxf(m, fmaxf(fmaxf(fabsf(v.x), fabsf(v.y)), fmaxf(fabsf(v.z), fabsf(v.w))));
    }
#pragma unroll
    for (int o = 32; o; o >>= 1) m = fmaxf(m, __shfl_xor(m, o));
    if ((threadIdx.x & 63) == 0) atomicMax(amax_bits, __float_as_uint(m));
}

// ---------------- derive scales ONCE ----------------
__global__ void fp8lin_scales(const unsigned* __restrict__ amax_bits,
                              const float* __restrict__ wscale,
                              float* __restrict__ scales) {
    float xs = fmaxf(__uint_as_float(*amax_bits), 1e-12f) / FP8_MAX_V;
    scales[0] = xs;
    scales[1] = xs * wscale[0];
}

// ---------------- probe weight transport dtype ----------------
__global__ void fp8lin_probe(const uint32_t* __restrict__ w, unsigned* __restrict__ flag) {
    __shared__ unsigned s32, s16, s4;
    if (threadIdx.x == 0) { s32 = 0u; s16 = 0u; s4 = 0u; }
    __syncthreads();
    unsigned o32 = 0u, o16 = 0u, o4 = 0u;
    for (int i = threadIdx.x; i < 4096; i += 256) {
        uint32_t v = w[i];
        o32 |= v & 0x000FFFFFu;
        uint32_t h0 = v & 0xFFFFu, h1 = v >> 16;
        o16 |= (h0 & 0x7Fu) | (h1 & 0x7Fu);
        o4  |= (h0 & 0x0Fu) | (h1 & 0x0Fu);
    }
    atomicOr(&s32, o32); atomicOr(&s16, o16); atomicOr(&s4, o4);
    __syncthreads();
    if (threadIdx.x == 0)
        *flag = (s32 == 0u) ? 0u : (s16 == 0u) ? 1u : (s4 == 0u) ? 2u : 3u;
}

// ---- convert + PACK weight into MFMA-fragment order ----
// pack unit (nt,kt) = 2048 B: lane l = r + 32q holds W[nt*32+r][kt*64+32q .. +32).
// GEMM B-load becomes 64 lanes x 32 B CONTIGUOUS (2 KB per wave-instruction);
// R10's row-major read was 32 cache lines per instruction (uncoalesced) -> -37%.
__global__ void fp8lin_packw(const void* __restrict__ wsrc, const unsigned* __restrict__ flag,
                             uint8_t* __restrict__ pack, int N, int K) {
    const int NKT = K >> 6;
    const long units = ((long)N * K) >> 6;   // one thread per 64-B k-chunk of one row
    unsigned f = *flag;
    long stride = (long)gridDim.x * blockDim.x;
    for (long u = blockIdx.x * (long)blockDim.x + threadIdx.x; u < units; u += stride) {
        int r = (int)(u & 31);
        long v = u >> 5;                     // nt*NKT + kt
        long row = (v / NKT) * 32 + r;
        long kbase = (long)(v % NKT) * 64;
        uint32_t wv[16];
        if (f == 0u) {
            const float* s = (const float*)wsrc + row * K + kbase;
#pragma unroll
            for (int i = 0; i < 16; ++i) {
                uint32_t a = 0;
#pragma unroll
                for (int j = 0; j < 4; ++j) a |= (uint32_t)cvt_fp8(s[4 * i + j]) << (8 * j);
                wv[i] = a;
            }
        } else if (f == 1u) {
            const __half* s = (const __half*)wsrc + row * K + kbase;
#pragma unroll
            for (int i = 0; i < 16; ++i) {
                uint32_t a = 0;
#pragma unroll
                for (int j = 0; j < 4; ++j) a |= (uint32_t)cvt_fp8(__half2float(s[4 * i + j])) << (8 * j);
                wv[i] = a;
            }
        } else if (f == 2u) {
            const uint16_t* s = (const uint16_t*)wsrc + row * K + kbase;
#pragma unroll
            for (int i = 0; i < 16; ++i) {
                uint32_t a = 0;
#pragma unroll
                for (int j = 0; j < 4; ++j)
                    a |= (uint32_t)cvt_fp8(__uint_as_float((uint32_t)s[4 * i + j] << 16)) << (8 * j);
                wv[i] = a;
            }
        } else {
            const uint32_t* s = (const uint32_t*)((const uint8_t*)wsrc + row * K + kbase);
#pragma unroll
            for (int i = 0; i < 16; ++i) wv[i] = s[i];
        }
        uint8_t* d0 = pack + (v * 64 + r) * 32;        // q=0 half
        uint8_t* d1 = pack + (v * 64 + 32 + r) * 32;   // q=1 half
        i32x4 lo0 = { (int)wv[0], (int)wv[1], (int)wv[2], (int)wv[3] };
        i32x4 lo1 = { (int)wv[4], (int)wv[5], (int)wv[6], (int)wv[7] };
        i32x4 hi0 = { (int)wv[8], (int)wv[9], (int)wv[10], (int)wv[11] };
        i32x4 hi1 = { (int)wv[12], (int)wv[13], (int)wv[14], (int)wv[15] };
        *(i32x4*)(d0) = lo0; *(i32x4*)(d0 + 16) = lo1;
        *(i32x4*)(d1) = hi0; *(i32x4*)(d1 + 16) = hi1;
    }
}

// ---------------- quantize x -> fp8 e4m3fn ----------------
__global__ void fp8lin_quant(const float4* __restrict__ x, const float* __restrict__ scales,
                             uchar4* __restrict__ xq, long n4) {
    float s = scales[0];
    long stride = (long)gridDim.x * blockDim.x;
    for (long i = blockIdx.x * (long)blockDim.x + threadIdx.x; i < n4; i += stride) {
        float4 v = x[i];
        uchar4 o;
        o.x = cvt_fp8(v.x / s); o.y = cvt_fp8(v.y / s);
        o.z = cvt_fp8(v.z / s); o.w = cvt_fp8(v.w / s);
        xq[i] = o;
    }
}

// ---- fp8 GEMM: 256x128 tile, 4 waves, MX 32x32x64, A via LDS dbuf, B from pack ----
#define BM 256
#define BN 128
#define BK 64
#define A_TILE 16384                  // 256 rows x 64 B
#define BUF_BYTES A_TILE              // A only in LDS
#define SMEM_BYTES (2 * BUF_BYTES)    // 32 KiB double-buffered

__device__ __forceinline__ void gload16(const uint8_t* src, uint8_t* ldst) {
    __builtin_amdgcn_global_load_lds(
        (const __attribute__((address_space(1))) uint32_t*)(uintptr_t)src,
        (__attribute__((address_space(3))) uint32_t*)(uintptr_t)ldst, 16, 0, 0);
}

#define WAITVM(N) asm volatile("s_waitcnt vmcnt(" #N ")" ::: "memory")
#define BARRIER() do { asm volatile("" ::: "memory"); __builtin_amdgcn_s_barrier(); \
                       asm volatile("" ::: "memory"); } while (0)

// load one 32B A-fragment from LDS (two ds_read_b128 at XOR-16 swizzled granules)
#define LDFRAG(dst, base, off) do {                                    \
    i32x4 _lo = *(const i32x4*)((base) + (off));                       \
    i32x4 _hi = *(const i32x4*)((base) + ((off) ^ 16));                \
    dst[0] = _lo[0]; dst[1] = _lo[1]; dst[2] = _lo[2]; dst[3] = _lo[3];\
    dst[4] = _hi[0]; dst[5] = _hi[1]; dst[6] = _hi[2]; dst[7] = _hi[3];\
} while (0)

// load one 32B B-fragment from PACKED weight (coalesced: wave reads 2 KB contig)
#define LOADB(bv, src, koff) do {                                      \
    const uint8_t* _p = (src) + (koff);                                \
    i32x4 _l0 = *(const i32x4*)(_p);                                   \
    i32x4 _l1 = *(const i32x4*)(_p + 16);                              \
    bv[0] = _l0[0]; bv[1] = _l0[1]; bv[2] = _l0[2]; bv[3] = _l0[3];    \
    bv[4] = _l1[0]; bv[5] = _l1[1]; bv[6] = _l1[2]; bv[7] = _l1[3];    \
} while (0)

// unit scales: e8m0 byte 0x7f = 2^0, every byte identical so opsel-immune
#define MFMA_MX(A, B, C) __builtin_amdgcn_mfma_scale_f32_32x32x64_f8f6f4( \
    (A), (B), (C), 0, 0, 0, (int)0x7f7f7f7f, 0, (int)0x7f7f7f7f)

// min-waves/EU = 2 (256-reg budget). Forcing 4 spilled the 128-reg acc (R6).
// 4-wave blocks, 2 independent blocks/CU (R8 mechanism); B bypasses LDS via pack.
__global__ __launch_bounds__(256, 2) void fp8lin_gemm(
    const uint8_t* __restrict__ Aq,    // [M,K] fp8
    const uint8_t* __restrict__ Bpack, // packed W fragments
    const float* __restrict__ scales,
    const float* __restrict__ bias,
    float* __restrict__ out,
    int M, int N, int K) {
    extern __shared__ __align__(16) uint8_t smem[];

    const int tid = threadIdx.x;
    const int wid = tid >> 6;
    const int lane = tid & 63;
    const int wm = wid >> 1;   // 0..1  (M-wave, 128 rows each)
    const int wn = wid & 1;    // 0..1  (N-wave, 64 cols each)

    // ---- bijective XCD swizzle ----
    const int nbx = gridDim.x;                       // 128
    const int orig = blockIdx.y * nbx + blockIdx.x;
    const int cpx = (gridDim.x * gridDim.y) >> 3;    // 512
    const int swzb = (orig & 7) * cpx + (orig >> 3);
    const int brow = (swzb / nbx) * BM;
    const int bcol = (swzb % nbx) * BN;

    // ---- A staging: LDS linear [row][4 granules of 16B]; granule p holds global
    // granule p ^ ((row>>1)&3)  (pre-swizzled source column) ----
    const uint8_t* srcA[4];
#pragma unroll
    for (int j = 0; j < 4; ++j) {
        int c = tid + 256 * j;
        int r = c >> 2;
        int sc = ((c & 3) ^ ((r >> 1) & 3)) * 16;
        srcA[j] = Aq + (size_t)(brow + r) * K + sc;
    }
    const int ldsW = wid * 1024;   // wave-uniform LDS base (lane*16 implicit)

    // ---- LDS read addressing for A fragments ----
    const int l31 = lane & 31;
    const int q = lane >> 5;
    const int swzr = (l31 >> 1) & 3;          // row-base is mult of 32
    const int posl = (2 * q) ^ swzr;
    const int offA = (wm * 128 + l31) * 64 + posl * 16;  // + mi*2048

    // ---- B from pack: n-tile = bcol/32 + wn*2 + ni; per-K-tile stride 2048 B ----
    const int NKT = K >> 6;
    const uint8_t* srcB0 = Bpack + ((size_t)((bcol >> 5) + wn * 2) * NKT * 64 + lane) * 32;
    const uint8_t* srcB1 = srcB0 + (size_t)NKT * 2048;

    f32x16 acc[4][2];
#pragma unroll
    for (int mi = 0; mi < 4; ++mi)
#pragma unroll
        for (int ni = 0; ni < 2; ++ni)
#pragma unroll
            for (int r = 0; r < 16; ++r) acc[mi][ni][r] = 0.0f;

    auto STAGEA = [&](int t, int ib) {
        size_t k0 = (size_t)t * BK;
        uint8_t* base = smem + ib * BUF_BYTES;
        gload16(srcA[0] + k0, base + ldsW);
        gload16(srcA[1] + k0, base + ldsW + 4096);
        gload16(srcA[2] + k0, base + ldsW + 8192);
        gload16(srcA[3] + k0, base + ldsW + 12288);
    };

    auto COMPUTE = [&](int ib, const i32x8& b0, const i32x8& b1) {
        const uint8_t* bA = smem + ib * BUF_BYTES;
        i32x8 a0, a1, a2, a3;
        LDFRAG(a0, bA, offA);
        LDFRAG(a1, bA, offA + 2048);
        __builtin_amdgcn_s_setprio(1);
        acc[0][0] = MFMA_MX(a0, b0, acc[0][0]);
        acc[1][0] = MFMA_MX(a1, b0, acc[1][0]);
        acc[0][1] = MFMA_MX(a0, b1, acc[0][1]);
        acc[1][1] = MFMA_MX(a1, b1, acc[1][1]);
        __builtin_amdgcn_s_setprio(0);
        LDFRAG(a2, bA, offA + 4096);
        LDFRAG(a3, bA, offA + 6144);
        __builtin_amdgcn_s_setprio(1);
        acc[2][0] = MFMA_MX(a2, b0, acc[2][0]);
        acc[3][0] = MFMA_MX(a3, b0, acc[3][0]);
        acc[2][1] = MFMA_MX(a2, b1, acc[2][1]);
        acc[3][1] = MFMA_MX(a3, b1, acc[3][1]);
        __builtin_amdgcn_s_setprio(0);
    };

    // Each tile's batch = exactly 8 VMEM ops (4 B dwordx4 + 4 gload16), so
    // WAITVM(8) drains precisely the previous tile's batch.
    const int NT = K / BK;  // 64 (even)
    i32x8 bE0, bE1, bO0, bO1;          // static names: even/odd tile B frags (rule #20)
    LOADB(bE0, srcB0, 0); LOADB(bE1, srcB1, 0);
    STAGEA(0, 0);
    for (int tp = 0; tp < NT; tp += 2) {
        // even tile tp: compute buf0/bE, prefetch tile tp+1 -> buf1/bO
        LOADB(bO0, srcB0, (size_t)(tp + 1) * 2048);
        LOADB(bO1, srcB1, (size_t)(tp + 1) * 2048);
        STAGEA(tp + 1, 1);
        WAITVM(8);
        BARRIER();
        COMPUTE(0, bE0, bE1);
        BARRIER();
        // odd tile tp+1: compute buf1/bO, prefetch tile tp+2 -> buf0/bE
        if (tp + 2 < NT) {
            LOADB(bE0, srcB0, (size_t)(tp + 2) * 2048);
            LOADB(bE1, srcB1, (size_t)(tp + 2) * 2048);
            STAGEA(tp + 2, 0);
            WAITVM(8);
        } else {
            WAITVM(0);
        }
        BARRIER();
        COMPUTE(1, bO0, bO1);
        BARRIER();
    }

    // ---- epilogue: 32x32 C/D layout col=lane&31, row=(reg&3)+8*(reg>>2)+4*q ----
    float s = scales[1];
    const int colg = bcol + wn * 64 + l31;
    const int rowg0 = brow + wm * 128 + 4 * q;
#pragma unroll
    for (int ni = 0; ni < 2; ++ni) {
        int col = colg + ni * 32;
        float bv = bias[col];
#pragma unroll
        for (int mi = 0; mi < 4; ++mi) {
            int rb = rowg0 + mi * 32;
#pragma unroll
            for (int reg = 0; reg < 16; ++reg) {
                int row = rb + (reg & 3) + 8 * (reg >> 2);
                __builtin_nontemporal_store(acc[mi][ni][reg] * s + bv,
                                            out + (size_t)row * N + col);
            }
        }
    }
}

extern "C" void kernel_launch(void* const* d_in, const int* in_sizes, int n_in,
                              void* d_out, int out_size, void* d_ws, size_t ws_size,
                              hipStream_t stream) {
    const float* x = (const float*)d_in[0];
    const void* w = d_in[1];
    const float* wscale = (const float*)d_in[2];
    const float* bias = (const float*)d_in[3];
    float* out = (float*)d_out;

    const int Bb = 4, S = 2048, K = 4096, N = 16384;
    const int M = Bb * S;
    const long nx = (long)M * K;
    const long nw = (long)N * K;

    unsigned* amax_bits = (unsigned*)d_ws;
    float* scales = (float*)((char*)d_ws + 16);
    unsigned* wflag = (unsigned*)((char*)d_ws + 32);
    uchar4* xq = (uchar4*)((char*)d_ws + 256);
    uint8_t* pack = (uint8_t*)((char*)d_ws + 256 + nx);

    fp8lin_init<<<1, 1, 0, stream>>>(amax_bits);
    fp8lin_probe<<<1, 256, 0, stream>>>((const uint32_t*)w, wflag);
    fp8lin_amax<<<2048, 256, 0, stream>>>((const float4*)x, amax_bits, nx / 4);
    fp8lin_scales<<<1, 1, 0, stream>>>(amax_bits, wscale, scales);
    fp8lin_quant<<<2048, 256, 0, stream>>>((const float4*)x, scales, xq, nx / 4);
    fp8lin_packw<<<2048, 256, 0, stream>>>(w, wflag, pack, N, K);

    dim3 grid(N / BN, M / BM);   // (128, 32) = 4096 blocks
    fp8lin_gemm<<<grid, 256, SMEM_BYTES, stream>>>((const uint8_t*)xq, pack,
                                                   scales, bias, out, M, N, K);
}